// Round 8
// baseline (157.279 us; speedup 1.0000x reference)
//
#include <hip/hip_runtime.h>

// Problem constants
#define N_PTS   65536      // B*H*W = 64*32*32
#define K_CODES 1024
#define C_DIM   64
#define HW      1024
#define Q_ELEMS 4194304
#define NBLOCKS 1024       // vq_main grid

// d_out layout (float32): [vq_loss(1) | quantized(4194304) | perplexity(1) | indices(65536)]
#define OUT_Q_OFF 1
#define OUT_P_OFF 4194305
#define OUT_I_OFF 4194306

// ws layout (bytes)
#define WS_HIST 0          // 1024 u32   (4096)
#define WS_CNT  4096       // 1 u32      (4)
#define WS_SSE  4104       // 1 double   (8)
#define WS_CSUM 4112       // 1024 f32   (4096)
#define WS_CBP  8208       // packed A-frags: 32 tiles * 9 slots * 512 shorts (294912)

// Screen metric w = x.c - csum/2 (argmin dist == argmax w). Proven thresholds
// (identical indices across R5-R7 structural variants):
#define EPS_A_W 7.5e-5f    // ambiguous if m2 >= m1 - EPS_A_W
#define EPS_T_W 2.0e-4f    // candidate tile if tmax >= m1 - EPS_T_W

typedef float f32x16 __attribute__((ext_vector_type(16)));
typedef short bf16x8 __attribute__((ext_vector_type(8)));

__device__ __forceinline__ unsigned short bf16rn(float f) {
    unsigned int u = __float_as_uint(f);
    return (unsigned short)((u + 0x7FFFu + ((u >> 16) & 1u)) >> 16);
}
__device__ __forceinline__ float bf16tof(unsigned short h) {
    return __uint_as_float(((unsigned int)h) << 16);
}

// numpy pairwise sum (n=64): 8 accumulators striding 8, then pairwise combine.
__device__ __forceinline__ float np_pairwise_sumsq64(const float* a) {
    float r[8];
    #pragma unroll
    for (int j = 0; j < 8; ++j) r[j] = __fmul_rn(a[j], a[j]);
    #pragma unroll
    for (int i = 8; i < 64; i += 8) {
        #pragma unroll
        for (int j = 0; j < 8; ++j)
            r[j] = __fadd_rn(r[j], __fmul_rn(a[i + j], a[i + j]));
    }
    return __fadd_rn(__fadd_rn(__fadd_rn(r[0], r[1]), __fadd_rn(r[2], r[3])),
                     __fadd_rn(__fadd_rn(r[4], r[5]), __fadd_rn(r[6], r[7])));
}

// Prep: one block per 32-code tile. Coalesced stage to LDS, then csum +
// packed split-bf16 A-frags (slot layout: 8 hi/lo chunk slots + csum slot).
__global__ void vq_prep(const float* __restrict__ cb, float* __restrict__ csum,
                        unsigned short* __restrict__ cbp) {
    __shared__ float rs[32 * 65];
    __shared__ float csl[32];
    const int t = blockIdx.x, tid = threadIdx.x;
    const float* src = cb + (size_t)t * 2048;
    for (int i = tid; i < 2048; i += 256) {
        int row = i >> 6, d = i & 63;
        rs[row * 65 + d] = src[i];
    }
    __syncthreads();
    if (tid < 32) {
        float cs = np_pairwise_sumsq64(&rs[tid * 65]);
        csum[t * 32 + tid] = cs;
        csl[tid] = cs;
    }
    __syncthreads();
    if (tid < 64) {
        int l31 = tid & 31, half = tid >> 5;
        const float* r = &rs[l31 * 65];
        unsigned short* dst = cbp + (size_t)t * 9 * 512;
        #pragma unroll
        for (int c = 0; c < 4; ++c) {
            bf16x8 h8, l8;
            #pragma unroll
            for (int j = 0; j < 8; ++j) {
                float f = r[c * 16 + half * 8 + j];
                unsigned short h = bf16rn(f);
                h8[j] = (short)h;
                l8[j] = (short)bf16rn(f - bf16tof(h));
            }
            *(bf16x8*)(dst + (size_t)(c * 2 + 0) * 512 + tid * 8) = h8;
            *(bf16x8*)(dst + (size_t)(c * 2 + 1) * 512 + tid * 8) = l8;
        }
        bf16x8 c8;
        #pragma unroll
        for (int j = 0; j < 8; ++j) c8[j] = 0;
        if (half == 0) c8[0] = (short)bf16rn(-0.5f * csl[l31]);
        *(bf16x8*)(dst + (size_t)8 * 512 + tid * 8) = c8;
    }
}

// Main: block = 64 points, 4 waves = (point-half pg x code-half chh); each
// wave screens 32 points vs 512 codes (16 tiles), 3 independent MFMA chains
// per tile (5/4/4). tmax bounds the exact rescan; ambiguous points resolved
// one-wave-per-point with the reference-bit-exact f32 pipeline. Last block
// (device-scope atomic counter) computes perplexity + loss — no extra kernel.
__global__ __launch_bounds__(256, 3) void vq_main(
        const float* __restrict__ latents,
        const float* __restrict__ cb,
        const float* __restrict__ csum,
        const unsigned short* __restrict__ cbp,
        unsigned int* __restrict__ hist,
        double* __restrict__ sse,
        unsigned int* __restrict__ counter,
        float* __restrict__ out) {
    __shared__ float xs[64 * 65];             // 16.6 KB
    __shared__ float tmax[32 * 64];           // 8 KB
    __shared__ float sm1[2][64], sm2[2][64];
    __shared__ int   si1[2][64];
    __shared__ float m1f[64];
    __shared__ int   fk[64], ambig[64];
    __shared__ int   acount, lastflag;
    __shared__ double red[256];               // last-block reduction

    const int tid  = threadIdx.x;
    const int lane = tid & 63, wave = tid >> 6;
    const int chh = wave & 1, pg = wave >> 1;
    const int n0 = blockIdx.x * 64;
    const int b = n0 >> 10, hw0 = n0 & 1023;
    const float* xg = latents + (size_t)b * C_DIM * HW + hw0;

    for (int i = tid; i < 64 * 64; i += 256) {
        int p = i & 63, d = i >> 6;
        xs[p * 65 + d] = xg[(size_t)d * HW + p];
    }
    if (tid == 0) acount = 0;
    __syncthreads();

    // B-frags: col = lane&31 -> point, k = (lane>>5)*8 + j
    const int l31 = lane & 31, half = lane >> 5;
    const int pb = (pg << 5) + l31;
    bf16x8 xh[4], xl[4], x4;
    #pragma unroll
    for (int c = 0; c < 4; ++c)
        #pragma unroll
        for (int j = 0; j < 8; ++j) {
            float f = xs[pb * 65 + c * 16 + half * 8 + j];
            unsigned short h = bf16rn(f);
            xh[c][j] = (short)h;
            xl[c][j] = (short)bf16rn(f - bf16tof(h));
        }
    #pragma unroll
    for (int j = 0; j < 8; ++j) x4[j] = 0;
    if (half == 0) x4[0] = (short)0x3F80;     // bf16(1.0) at k=64

    float m1 = -3e38f, m2 = -3e38f;
    int i1 = 0;
    const int RC[16] = {0,1,2,3,8,9,10,11,16,17,18,19,24,25,26,27};
    const int rh4 = half * 4;

    for (int t = 0; t < 16; ++t) {
        const int tg = (chh << 4) + t;
        const bf16x8* bp = (const bf16x8*)cbp + (size_t)tg * 576 + lane;
        bf16x8 ch[4], cl[4], ca;
        #pragma unroll
        for (int c = 0; c < 4; ++c) {
            ch[c] = bp[c * 128];
            cl[c] = bp[c * 128 + 64];
        }
        ca = bp[512];
        f32x16 accA, accB1, accB2;
        #pragma unroll
        for (int r = 0; r < 16; ++r) { accA[r] = 0.0f; accB1[r] = 0.0f; accB2[r] = 0.0f; }
        #pragma unroll
        for (int c = 0; c < 4; ++c)
            accA = __builtin_amdgcn_mfma_f32_32x32x16_bf16(ch[c], xh[c], accA, 0, 0, 0);
        accA = __builtin_amdgcn_mfma_f32_32x32x16_bf16(ca, x4, accA, 0, 0, 0);
        #pragma unroll
        for (int c = 0; c < 4; ++c)
            accB1 = __builtin_amdgcn_mfma_f32_32x32x16_bf16(ch[c], xl[c], accB1, 0, 0, 0);
        #pragma unroll
        for (int c = 0; c < 4; ++c)
            accB2 = __builtin_amdgcn_mfma_f32_32x32x16_bf16(cl[c], xh[c], accB2, 0, 0, 0);
        float tl = -3e38f;
        const int tb2 = tg << 5;
        #pragma unroll
        for (int r = 0; r < 16; ++r) {
            float v = __fadd_rn(__fadd_rn(accA[r], accB1[r]), accB2[r]);
            int k = tb2 + RC[r] + rh4;
            m2 = fmaxf(m2, fminf(m1, v));
            i1 = (v > m1) ? k : i1;           // strict >: first-max = ref tie-break
            m1 = fmaxf(m1, v);
            tl = fmaxf(tl, v);
        }
        tl = fmaxf(tl, __shfl_xor(tl, 32, 64));
        if (half == 0) tmax[tg * 64 + pb] = tl;
    }
    // merge half-wave row-sets, publish per code-half
    {
        float m1o = __shfl_xor(m1, 32, 64);
        float m2o = __shfl_xor(m2, 32, 64);
        int   i1o = __shfl_xor(i1, 32, 64);
        m2 = fmaxf(fmaxf(m2, m2o), fminf(m1, m1o));
        i1 = (m1o > m1) ? i1o : i1;
        m1 = fmaxf(m1, m1o);
        if (half == 0) { sm1[chh][pb] = m1; sm2[chh][pb] = m2; si1[chh][pb] = i1; }
    }
    __syncthreads();

    // cross code-half merge + ambiguity test (ties -> rescan)
    if (tid < 64) {
        float a1 = sm1[0][tid], a2 = sm2[0][tid];
        float b1 = sm1[1][tid], b2 = sm2[1][tid];
        float mm1 = fmaxf(a1, b1);
        float mm2 = fmaxf(fminf(a1, b1), fmaxf(a2, b2));
        m1f[tid] = mm1;
        fk[tid] = (b1 > a1) ? si1[1][tid] : si1[0][tid];
        if (mm2 >= mm1 - EPS_A_W) {
            int a = atomicAdd(&acount, 1);
            ambig[a] = tid;
        }
    }
    __syncthreads();

    // Exact rescan: one wave per ambiguous point, candidate tiles only.
    // Reference-bit-exact: dist = fl32(fl32(A+csum[k]) - fl32(2*seqFMA)).
    for (int a = wave; a < acount; a += 4) {
        int p = ambig[a];
        const float* xrow = &xs[p * 65];
        float Aq = np_pairwise_sumsq64(xrow);
        float thr = m1f[p] - EPS_T_W;
        unsigned long long best = ~0ULL;
        for (int t = 0; t < 32; ++t) {
            if (tmax[t * 64 + p] < thr) continue;    // wave-uniform branch
            if (lane < 32) {
                int k = (t << 5) + lane;
                const float* crow = cb + (size_t)k * 64;
                float m = 0.0f;
                #pragma unroll
                for (int d = 0; d < 64; ++d) m = __fmaf_rn(xrow[d], crow[d], m);
                float D = __fsub_rn(__fadd_rn(Aq, csum[k]), __fmul_rn(2.0f, m));
                unsigned long long key =
                    ((unsigned long long)__float_as_uint(D) << 10) | (unsigned)k;
                best = (key < best) ? key : best;
            }
        }
        #pragma unroll
        for (int off = 32; off > 0; off >>= 1) {
            unsigned long long o = __shfl_xor(best, off, 64);
            best = (o < best) ? o : best;
        }
        if (lane == 0) fk[p] = (int)(best & 1023ULL);
    }
    __syncthreads();

    // indices + histogram + SSE (wave 0 = tid<64, one point per lane)
    if (tid < 64) {
        int myk = fk[tid];
        out[OUT_I_OFF + n0 + tid] = (float)myk;
        atomicAdd(&hist[myk], 1u);
        const float* crow = cb + (size_t)myk * 64;
        const float* xrow = &xs[tid * 65];
        double e = 0.0;
        #pragma unroll
        for (int d = 0; d < 64; ++d) {
            double df = (double)xrow[d] - (double)crow[d];
            e = fma(df, df, e);
        }
        #pragma unroll
        for (int off = 32; off > 0; off >>= 1) e += __shfl_down(e, off, 64);
        if (tid == 0) atomicAdd(sse, e);
    }
    // quantized [B,C,H,W]: coalesced 64-float rows per c
    for (int i = tid; i < 64 * 64; i += 256) {
        int p = i & 63, c = i >> 6;
        out[OUT_Q_OFF + (size_t)b * 65536 + (size_t)c * HW + hw0 + p] =
            cb[(size_t)fk[p] * 64 + c];
    }

    // Last-block finalization. __syncthreads drains vmcnt -> this block's
    // hist/sse atomics are globally performed before the counter bump.
    __syncthreads();
    if (tid == 0) lastflag = (atomicAdd(counter, 1u) == NBLOCKS - 1) ? 1 : 0;
    __syncthreads();
    if (lastflag) {
        double s = 0.0;
        for (int i = tid; i < K_CODES; i += 256) {
            double p = (double)atomicAdd(&hist[i], 0u) / (double)N_PTS;
            s += p * log(p + 1e-10);
        }
        red[tid] = s;
        __syncthreads();
        for (int w = 128; w > 0; w >>= 1) {
            if (tid < w) red[tid] += red[tid + w];
            __syncthreads();
        }
        if (tid == 0) {
            out[OUT_P_OFF] = (float)exp(-red[0]);
            double sv = atomicAdd(sse, 0.0);
            out[0] = (float)(1.25 * sv / (double)Q_ELEMS);
        }
    }
}

extern "C" void kernel_launch(void* const* d_in, const int* in_sizes, int n_in,
                              void* d_out, int out_size, void* d_ws, size_t ws_size,
                              hipStream_t stream) {
    const float* latents = (const float*)d_in[0];
    const float* cb      = (const float*)d_in[1];
    float* out = (float*)d_out;
    char* ws = (char*)d_ws;

    unsigned int*   hist    = (unsigned int*)(ws + WS_HIST);
    unsigned int*   counter = (unsigned int*)(ws + WS_CNT);
    double*         sse     = (double*)(ws + WS_SSE);
    float*          csum    = (float*)(ws + WS_CSUM);
    unsigned short* cbp     = (unsigned short*)(ws + WS_CBP);

    hipMemsetAsync(ws, 0, 4112, stream);      // hist + counter + sse

    vq_prep <<<32, 256, 0, stream>>>(cb, csum, cbp);
    vq_main <<<NBLOCKS, 256, 0, stream>>>(latents, cb, csum, cbp, hist, sse, counter, out);
}

// Round 9
// 152.371 us; speedup vs baseline: 1.0322x; 1.0322x over previous
//
#include <hip/hip_runtime.h>

// Problem constants
#define N_PTS   65536      // B*H*W = 64*32*32
#define K_CODES 1024
#define C_DIM   64
#define HW      1024
#define Q_ELEMS 4194304
#define NBLOCKS 1024       // vq_main grid

// d_out layout (float32): [vq_loss(1) | quantized(4194304) | perplexity(1) | indices(65536)]
#define OUT_Q_OFF 1
#define OUT_P_OFF 4194305
#define OUT_I_OFF 4194306

// ws layout (bytes)
#define WS_HIST 0          // 1024 u32   (4096)
#define WS_CNT  4096       // 1 u32      (4)
#define WS_SSE  4104       // 1 double   (8)
#define WS_CSUM 4112       // 1024 f32   (4096)
#define WS_CBP  8208       // packed A-frags: 32 tiles * 9 slots * 512 shorts (294912)

// Screen metric w = x.c - csum/2 (argmin dist == argmax w). Proven thresholds
// (identical indices across R5-R8 structural variants):
#define EPS_A_W 7.5e-5f    // ambiguous if m2 >= m1 - EPS_A_W
#define EPS_T_W 2.0e-4f    // candidate tile if tmax >= m1 - EPS_T_W

typedef float f32x16 __attribute__((ext_vector_type(16)));
typedef short bf16x8 __attribute__((ext_vector_type(8)));

__device__ __forceinline__ unsigned short bf16rn(float f) {
    unsigned int u = __float_as_uint(f);
    return (unsigned short)((u + 0x7FFFu + ((u >> 16) & 1u)) >> 16);
}
__device__ __forceinline__ float bf16tof(unsigned short h) {
    return __uint_as_float(((unsigned int)h) << 16);
}

// numpy pairwise sum (n=64): 8 accumulators striding 8, then pairwise combine.
__device__ __forceinline__ float np_pairwise_sumsq64(const float* a) {
    float r[8];
    #pragma unroll
    for (int j = 0; j < 8; ++j) r[j] = __fmul_rn(a[j], a[j]);
    #pragma unroll
    for (int i = 8; i < 64; i += 8) {
        #pragma unroll
        for (int j = 0; j < 8; ++j)
            r[j] = __fadd_rn(r[j], __fmul_rn(a[i + j], a[i + j]));
    }
    return __fadd_rn(__fadd_rn(__fadd_rn(r[0], r[1]), __fadd_rn(r[2], r[3])),
                     __fadd_rn(__fadd_rn(r[4], r[5]), __fadd_rn(r[6], r[7])));
}

// Prep: one block per 32-code tile. Also zeroes hist/counter/sse (no memset
// node needed). Coalesced stage to LDS, then csum + packed split-bf16 A-frags.
__global__ void vq_prep(const float* __restrict__ cb, float* __restrict__ csum,
                        unsigned short* __restrict__ cbp,
                        unsigned int* __restrict__ hist,
                        unsigned int* __restrict__ counter,
                        double* __restrict__ sse) {
    __shared__ float rs[32 * 65];
    __shared__ float csl[32];
    const int t = blockIdx.x, tid = threadIdx.x;
    // zero accumulators: block t handles hist[32t..32t+32); block 0 cnt+sse
    if (tid < 32) hist[t * 32 + tid] = 0u;
    if (t == 0 && tid == 0) { *counter = 0u; *sse = 0.0; }
    const float* src = cb + (size_t)t * 2048;
    for (int i = tid; i < 2048; i += 256) {
        int row = i >> 6, d = i & 63;
        rs[row * 65 + d] = src[i];
    }
    __syncthreads();
    if (tid < 32) {
        float cs = np_pairwise_sumsq64(&rs[tid * 65]);
        csum[t * 32 + tid] = cs;
        csl[tid] = cs;
    }
    __syncthreads();
    if (tid < 64) {
        int l31 = tid & 31, half = tid >> 5;
        const float* r = &rs[l31 * 65];
        unsigned short* dst = cbp + (size_t)t * 9 * 512;
        #pragma unroll
        for (int c = 0; c < 4; ++c) {
            bf16x8 h8, l8;
            #pragma unroll
            for (int j = 0; j < 8; ++j) {
                float f = r[c * 16 + half * 8 + j];
                unsigned short h = bf16rn(f);
                h8[j] = (short)h;
                l8[j] = (short)bf16rn(f - bf16tof(h));
            }
            *(bf16x8*)(dst + (size_t)(c * 2 + 0) * 512 + tid * 8) = h8;
            *(bf16x8*)(dst + (size_t)(c * 2 + 1) * 512 + tid * 8) = l8;
        }
        bf16x8 c8;
        #pragma unroll
        for (int j = 0; j < 8; ++j) c8[j] = 0;
        if (half == 0) c8[0] = (short)bf16rn(-0.5f * csl[l31]);
        *(bf16x8*)(dst + (size_t)8 * 512 + tid * 8) = c8;
    }
}

// Main: block = 64 points, 4 waves = (point-half pg x code-half chh); each
// wave screens 32 points vs 512 codes (16 tiles), 3 independent MFMA chains
// per tile (5/4/4). tmax bounds the exact rescan; ambiguous points resolved
// one-wave-per-point with the reference-bit-exact f32 pipeline. Last block
// (device-scope atomic counter) computes perplexity + loss.
// launch_bounds(256,2): DO NOT raise — (256,3) forced VGPR=60 -> AGPR spills
// and a 97us regression (R8); ~88 VGPRs is this kernel's natural fit.
__global__ __launch_bounds__(256, 2) void vq_main(
        const float* __restrict__ latents,
        const float* __restrict__ cb,
        const float* __restrict__ csum,
        const unsigned short* __restrict__ cbp,
        unsigned int* __restrict__ hist,
        double* __restrict__ sse,
        unsigned int* __restrict__ counter,
        float* __restrict__ out) {
    __shared__ float xs[64 * 65];             // 16.6 KB; x tile, later q tile
    __shared__ float tmax[32 * 64];           // 8 KB
    __shared__ float sm1[2][64], sm2[2][64];
    __shared__ int   si1[2][64];
    __shared__ float m1f[64];
    __shared__ int   fk[64], ambig[64];
    __shared__ int   acount, lastflag;
    __shared__ double red[256];

    const int tid  = threadIdx.x;
    const int lane = tid & 63, wave = tid >> 6;
    const int chh = wave & 1, pg = wave >> 1;
    const int n0 = blockIdx.x * 64;
    const int b = n0 >> 10, hw0 = n0 & 1023;
    const float* xg = latents + (size_t)b * C_DIM * HW + hw0;

    for (int i = tid; i < 64 * 64; i += 256) {
        int p = i & 63, d = i >> 6;
        xs[p * 65 + d] = xg[(size_t)d * HW + p];
    }
    if (tid == 0) acount = 0;
    __syncthreads();

    // B-frags: col = lane&31 -> point, k = (lane>>5)*8 + j
    const int l31 = lane & 31, half = lane >> 5;
    const int pb = (pg << 5) + l31;
    bf16x8 xh[4], xl[4], x4;
    #pragma unroll
    for (int c = 0; c < 4; ++c)
        #pragma unroll
        for (int j = 0; j < 8; ++j) {
            float f = xs[pb * 65 + c * 16 + half * 8 + j];
            unsigned short h = bf16rn(f);
            xh[c][j] = (short)h;
            xl[c][j] = (short)bf16rn(f - bf16tof(h));
        }
    #pragma unroll
    for (int j = 0; j < 8; ++j) x4[j] = 0;
    if (half == 0) x4[0] = (short)0x3F80;     // bf16(1.0) at k=64

    float m1 = -3e38f, m2 = -3e38f;
    int i1 = 0;
    const int RC[16] = {0,1,2,3,8,9,10,11,16,17,18,19,24,25,26,27};
    const int rh4 = half * 4;

    for (int t = 0; t < 16; ++t) {
        const int tg = (chh << 4) + t;
        const bf16x8* bp = (const bf16x8*)cbp + (size_t)tg * 576 + lane;
        bf16x8 ch[4], cl[4], ca;
        #pragma unroll
        for (int c = 0; c < 4; ++c) {
            ch[c] = bp[c * 128];
            cl[c] = bp[c * 128 + 64];
        }
        ca = bp[512];
        f32x16 accA, accB1, accB2;
        #pragma unroll
        for (int r = 0; r < 16; ++r) { accA[r] = 0.0f; accB1[r] = 0.0f; accB2[r] = 0.0f; }
        #pragma unroll
        for (int c = 0; c < 4; ++c)
            accA = __builtin_amdgcn_mfma_f32_32x32x16_bf16(ch[c], xh[c], accA, 0, 0, 0);
        accA = __builtin_amdgcn_mfma_f32_32x32x16_bf16(ca, x4, accA, 0, 0, 0);
        #pragma unroll
        for (int c = 0; c < 4; ++c)
            accB1 = __builtin_amdgcn_mfma_f32_32x32x16_bf16(ch[c], xl[c], accB1, 0, 0, 0);
        #pragma unroll
        for (int c = 0; c < 4; ++c)
            accB2 = __builtin_amdgcn_mfma_f32_32x32x16_bf16(cl[c], xh[c], accB2, 0, 0, 0);
        float tl = -3e38f;
        const int tb2 = tg << 5;
        #pragma unroll
        for (int r = 0; r < 16; ++r) {
            float v = __fadd_rn(__fadd_rn(accA[r], accB1[r]), accB2[r]);
            int k = tb2 + RC[r] + rh4;
            m2 = fmaxf(m2, fminf(m1, v));
            i1 = (v > m1) ? k : i1;           // strict >: first-max = ref tie-break
            m1 = fmaxf(m1, v);
            tl = fmaxf(tl, v);
        }
        tl = fmaxf(tl, __shfl_xor(tl, 32, 64));
        if (half == 0) tmax[tg * 64 + pb] = tl;
    }
    // merge half-wave row-sets, publish per code-half
    {
        float m1o = __shfl_xor(m1, 32, 64);
        float m2o = __shfl_xor(m2, 32, 64);
        int   i1o = __shfl_xor(i1, 32, 64);
        m2 = fmaxf(fmaxf(m2, m2o), fminf(m1, m1o));
        i1 = (m1o > m1) ? i1o : i1;
        m1 = fmaxf(m1, m1o);
        if (half == 0) { sm1[chh][pb] = m1; sm2[chh][pb] = m2; si1[chh][pb] = i1; }
    }
    __syncthreads();

    // cross code-half merge + ambiguity test (ties -> rescan)
    if (tid < 64) {
        float a1 = sm1[0][tid], a2 = sm2[0][tid];
        float b1 = sm1[1][tid], b2 = sm2[1][tid];
        float mm1 = fmaxf(a1, b1);
        float mm2 = fmaxf(fminf(a1, b1), fmaxf(a2, b2));
        m1f[tid] = mm1;
        fk[tid] = (b1 > a1) ? si1[1][tid] : si1[0][tid];
        if (mm2 >= mm1 - EPS_A_W) {
            int a = atomicAdd(&acount, 1);
            ambig[a] = tid;
        }
    }
    __syncthreads();

    // Exact rescan: one wave per ambiguous point, candidate tiles only.
    // Reference-bit-exact: dist = fl32(fl32(A+csum[k]) - fl32(2*seqFMA)).
    for (int a = wave; a < acount; a += 4) {
        int p = ambig[a];
        const float* xrow = &xs[p * 65];
        float Aq = np_pairwise_sumsq64(xrow);
        float thr = m1f[p] - EPS_T_W;
        unsigned long long best = ~0ULL;
        for (int t = 0; t < 32; ++t) {
            if (tmax[t * 64 + p] < thr) continue;    // wave-uniform branch
            if (lane < 32) {
                int k = (t << 5) + lane;
                const float* crow = cb + (size_t)k * 64;
                float m = 0.0f;
                #pragma unroll
                for (int d = 0; d < 64; ++d) m = __fmaf_rn(xrow[d], crow[d], m);
                float D = __fsub_rn(__fadd_rn(Aq, csum[k]), __fmul_rn(2.0f, m));
                unsigned long long key =
                    ((unsigned long long)__float_as_uint(D) << 10) | (unsigned)k;
                best = (key < best) ? key : best;
            }
        }
        #pragma unroll
        for (int off = 32; off > 0; off >>= 1) {
            unsigned long long o = __shfl_xor(best, off, 64);
            best = (o < best) ? o : best;
        }
        if (lane == 0) fk[p] = (int)(best & 1023ULL);
    }
    __syncthreads();

    // indices + histogram
    if (tid < 64) {
        out[OUT_I_OFF + n0 + tid] = (float)fk[tid];
        atomicAdd(&hist[fk[tid]], 1u);
    }

    // Quantized gather (coalesced: one cb row per wave-instruction) fused with
    // SSE accumulation; q overwrites xs in place (each slot owned by 1 thread).
    {
        double e = 0.0;
        #pragma unroll
        for (int it = 0; it < 16; ++it) {
            int i = tid + it * 256;
            int p = i >> 6, c = i & 63;           // c across lanes -> coalesced
            float q = cb[(size_t)fk[p] * 64 + c];
            float xv = xs[p * 65 + c];
            double df = (double)xv - (double)q;
            e = fma(df, df, e);
            xs[p * 65 + c] = q;
        }
        red[tid] = e;
    }
    __syncthreads();
    if (tid < 128) red[tid] += red[tid + 128];
    __syncthreads();
    if (tid < 64) {
        double v = red[tid] + red[tid + 64];
        #pragma unroll
        for (int off = 32; off > 0; off >>= 1) v += __shfl_down(v, off, 64);
        if (tid == 0) atomicAdd(sse, v);
    }
    // Quantized stores: p across lanes -> coalesced 256B rows; LDS bank
    // (p*65+c)%32 = (p+c)%32 -> free 2-way.
    #pragma unroll
    for (int it = 0; it < 16; ++it) {
        int i = tid + it * 256;
        int p = i & 63, c = i >> 6;
        out[OUT_Q_OFF + (size_t)b * 65536 + (size_t)c * HW + hw0 + p] = xs[p * 65 + c];
    }

    // Last-block finalization. __syncthreads drains vmcnt -> this block's
    // hist/sse atomics are globally performed before the counter bump.
    __syncthreads();
    if (tid == 0) lastflag = (atomicAdd(counter, 1u) == NBLOCKS - 1) ? 1 : 0;
    __syncthreads();
    if (lastflag) {
        double s = 0.0;
        for (int i = tid; i < K_CODES; i += 256) {
            double p = (double)atomicAdd(&hist[i], 0u) / (double)N_PTS;
            s += p * log(p + 1e-10);
        }
        red[tid] = s;
        __syncthreads();
        for (int w = 128; w > 0; w >>= 1) {
            if (tid < w) red[tid] += red[tid + w];
            __syncthreads();
        }
        if (tid == 0) {
            out[OUT_P_OFF] = (float)exp(-red[0]);
            double sv = atomicAdd(sse, 0.0);
            out[0] = (float)(1.25 * sv / (double)Q_ELEMS);
        }
    }
}

extern "C" void kernel_launch(void* const* d_in, const int* in_sizes, int n_in,
                              void* d_out, int out_size, void* d_ws, size_t ws_size,
                              hipStream_t stream) {
    const float* latents = (const float*)d_in[0];
    const float* cb      = (const float*)d_in[1];
    float* out = (float*)d_out;
    char* ws = (char*)d_ws;

    unsigned int*   hist    = (unsigned int*)(ws + WS_HIST);
    unsigned int*   counter = (unsigned int*)(ws + WS_CNT);
    double*         sse     = (double*)(ws + WS_SSE);
    float*          csum    = (float*)(ws + WS_CSUM);
    unsigned short* cbp     = (unsigned short*)(ws + WS_CBP);

    vq_prep <<<32, 256, 0, stream>>>(cb, csum, cbp, hist, counter, sse);
    vq_main <<<NBLOCKS, 256, 0, stream>>>(latents, cb, csum, cbp, hist, sse, counter, out);
}

// Round 10
// 147.941 us; speedup vs baseline: 1.0631x; 1.0299x over previous
//
#include <hip/hip_runtime.h>

// Problem constants
#define N_PTS   65536      // B*H*W = 64*32*32
#define K_CODES 1024
#define C_DIM   64
#define HW      1024
#define Q_ELEMS 4194304
#define NBLOCKS 512        // vq_main grid (128 points per block)

// d_out layout (float32): [vq_loss(1) | quantized(4194304) | perplexity(1) | indices(65536)]
#define OUT_Q_OFF 1
#define OUT_P_OFF 4194305
#define OUT_I_OFF 4194306

// ws layout (bytes)
#define WS_HIST 0          // 1024 u32   (4096)
#define WS_CNT  4096       // 1 u32      (4)
#define WS_SSE  4104       // 1 double   (8)
#define WS_CSUM 4112       // 1024 f32   (4096)
#define WS_CBP  8208       // packed A-frags: 32 tiles * 9 slots * 512 shorts (294912)

// Screen metric w = x.c - csum/2 (argmin dist == argmax w). Proven thresholds
// (identical indices across R5-R9 structural variants):
#define EPS_A_W 7.5e-5f    // ambiguous if m2 >= m1 - EPS_A_W
#define EPS_T_W 2.0e-4f    // candidate tile if tmax >= m1 - EPS_T_W

typedef float f32x16 __attribute__((ext_vector_type(16)));
typedef short bf16x8 __attribute__((ext_vector_type(8)));

__device__ __forceinline__ unsigned short bf16rn(float f) {
    unsigned int u = __float_as_uint(f);
    return (unsigned short)((u + 0x7FFFu + ((u >> 16) & 1u)) >> 16);
}
__device__ __forceinline__ float bf16tof(unsigned short h) {
    return __uint_as_float(((unsigned int)h) << 16);
}

// numpy pairwise sum (n=64): 8 accumulators striding 8, then pairwise combine.
__device__ __forceinline__ float np_pairwise_sumsq64(const float* a) {
    float r[8];
    #pragma unroll
    for (int j = 0; j < 8; ++j) r[j] = __fmul_rn(a[j], a[j]);
    #pragma unroll
    for (int i = 8; i < 64; i += 8) {
        #pragma unroll
        for (int j = 0; j < 8; ++j)
            r[j] = __fadd_rn(r[j], __fmul_rn(a[i + j], a[i + j]));
    }
    return __fadd_rn(__fadd_rn(__fadd_rn(r[0], r[1]), __fadd_rn(r[2], r[3])),
                     __fadd_rn(__fadd_rn(r[4], r[5]), __fadd_rn(r[6], r[7])));
}

// Prep: one block per 32-code tile; also zeroes hist/counter/sse.
__global__ void vq_prep(const float* __restrict__ cb, float* __restrict__ csum,
                        unsigned short* __restrict__ cbp,
                        unsigned int* __restrict__ hist,
                        unsigned int* __restrict__ counter,
                        double* __restrict__ sse) {
    __shared__ float rs[32 * 65];
    __shared__ float csl[32];
    const int t = blockIdx.x, tid = threadIdx.x;
    if (tid < 32) hist[t * 32 + tid] = 0u;
    if (t == 0 && tid == 0) { *counter = 0u; *sse = 0.0; }
    const float* src = cb + (size_t)t * 2048;
    for (int i = tid; i < 2048; i += 256) {
        int row = i >> 6, d = i & 63;
        rs[row * 65 + d] = src[i];
    }
    __syncthreads();
    if (tid < 32) {
        float cs = np_pairwise_sumsq64(&rs[tid * 65]);
        csum[t * 32 + tid] = cs;
        csl[tid] = cs;
    }
    __syncthreads();
    if (tid < 64) {
        int l31 = tid & 31, half = tid >> 5;
        const float* r = &rs[l31 * 65];
        unsigned short* dst = cbp + (size_t)t * 9 * 512;
        #pragma unroll
        for (int c = 0; c < 4; ++c) {
            bf16x8 h8, l8;
            #pragma unroll
            for (int j = 0; j < 8; ++j) {
                float f = r[c * 16 + half * 8 + j];
                unsigned short h = bf16rn(f);
                h8[j] = (short)h;
                l8[j] = (short)bf16rn(f - bf16tof(h));
            }
            *(bf16x8*)(dst + (size_t)(c * 2 + 0) * 512 + tid * 8) = h8;
            *(bf16x8*)(dst + (size_t)(c * 2 + 1) * 512 + tid * 8) = l8;
        }
        bf16x8 c8;
        #pragma unroll
        for (int j = 0; j < 8; ++j) c8[j] = 0;
        if (half == 0) c8[0] = (short)bf16rn(-0.5f * csl[l31]);
        *(bf16x8*)(dst + (size_t)8 * 512 + tid * 8) = c8;
    }
}

// Main (R7 skeleton, measured 73us): block = 128 points, 4 waves; each wave
// owns 32 points and screens ALL 32 code-tiles with double-buffered packed
// A-frag loads + 3 independent MFMA chains (5/4/4). Per-tile argmax chain is
// split r<8 / r>=8 (exact first-max via lex merge: chain-a k's < chain-b k's
// within a tile). Ambiguous points (m2 >= m1-eps) rescanned by the OWNING
// wave via ballot, candidate tiles only, reference-bit-exact f32 pipeline.
// Last block (device-scope counter) computes perplexity + loss.
__global__ __launch_bounds__(256, 2) void vq_main(
        const float* __restrict__ latents,
        const float* __restrict__ cb,
        const float* __restrict__ csum,
        const unsigned short* __restrict__ cbp,
        unsigned int* __restrict__ hist,
        double* __restrict__ sse,
        unsigned int* __restrict__ counter,
        float* __restrict__ out) {
    __shared__ float xs[128 * 65];            // 33.3 KB; x tile, later q tile
    __shared__ float tmax[32 * 128];          // 16 KB per-(tile,point) screen max
    __shared__ int   fk[128];
    __shared__ int   lastflag;
    __shared__ double red[256];

    const int tid  = threadIdx.x;
    const int lane = tid & 63, wave = tid >> 6;
    const int n0 = blockIdx.x * 128;
    const int b = n0 >> 10, hw0 = n0 & 1023;
    const float* xg = latents + (size_t)b * C_DIM * HW + hw0;

    for (int i = tid; i < 128 * 64; i += 256) {
        int p = i & 127, d = i >> 7;
        xs[p * 65 + d] = xg[(size_t)d * HW + p];
    }
    __syncthreads();

    // B-frags: col = lane&31 -> point, k = (lane>>5)*8 + j
    const int l31 = lane & 31, half = lane >> 5;
    const int pb = (wave << 5) + l31;         // this lane's block-point
    bf16x8 xh[4], xl[4], x4;
    #pragma unroll
    for (int c = 0; c < 4; ++c)
        #pragma unroll
        for (int j = 0; j < 8; ++j) {
            float f = xs[pb * 65 + c * 16 + half * 8 + j];
            unsigned short h = bf16rn(f);
            xh[c][j] = (short)h;
            xl[c][j] = (short)bf16rn(f - bf16tof(h));
        }
    #pragma unroll
    for (int j = 0; j < 8; ++j) x4[j] = 0;
    if (half == 0) x4[0] = (short)0x3F80;     // bf16(1.0) at k=64

    float m1a = -3e38f, m2a = -3e38f, m1b = -3e38f, m2b = -3e38f;
    int i1a = 0, i1b = 0;
    const int RC[16] = {0,1,2,3,8,9,10,11,16,17,18,19,24,25,26,27};
    const int rh4 = half * 4;
    const bf16x8* base = (const bf16x8*)cbp;

    auto load_tile = [&](int t, bf16x8* ch, bf16x8* cl, bf16x8& ca) {
        const bf16x8* bp = base + (size_t)t * 576 + lane;
        #pragma unroll
        for (int c = 0; c < 4; ++c) {
            ch[c] = bp[c * 128];
            cl[c] = bp[c * 128 + 64];
        }
        ca = bp[512];
    };
    auto screen_tile = [&](int t, const bf16x8* ch, const bf16x8* cl, bf16x8 ca) {
        f32x16 accA, accB1, accB2;
        #pragma unroll
        for (int r = 0; r < 16; ++r) { accA[r] = 0.0f; accB1[r] = 0.0f; accB2[r] = 0.0f; }
        #pragma unroll
        for (int c = 0; c < 4; ++c)
            accA = __builtin_amdgcn_mfma_f32_32x32x16_bf16(ch[c], xh[c], accA, 0, 0, 0);
        accA = __builtin_amdgcn_mfma_f32_32x32x16_bf16(ca, x4, accA, 0, 0, 0);
        #pragma unroll
        for (int c = 0; c < 4; ++c)
            accB1 = __builtin_amdgcn_mfma_f32_32x32x16_bf16(ch[c], xl[c], accB1, 0, 0, 0);
        #pragma unroll
        for (int c = 0; c < 4; ++c)
            accB2 = __builtin_amdgcn_mfma_f32_32x32x16_bf16(cl[c], xh[c], accB2, 0, 0, 0);
        const int tb2 = t << 5;
        float tla = -3e38f, tlb = -3e38f;
        #pragma unroll
        for (int r = 0; r < 8; ++r) {         // chain a: k in {0..3,8..11}+rh4
            float v = __fadd_rn(__fadd_rn(accA[r], accB1[r]), accB2[r]);
            int k = tb2 + RC[r] + rh4;
            m2a = fmaxf(m2a, fminf(m1a, v));
            i1a = (v > m1a) ? k : i1a;        // strict >: first-max within chain
            m1a = fmaxf(m1a, v);
            tla = fmaxf(tla, v);
        }
        #pragma unroll
        for (int r = 8; r < 16; ++r) {        // chain b: k in {16..19,24..27}+rh4
            float v = __fadd_rn(__fadd_rn(accA[r], accB1[r]), accB2[r]);
            int k = tb2 + RC[r] + rh4;
            m2b = fmaxf(m2b, fminf(m1b, v));
            i1b = (v > m1b) ? k : i1b;
            m1b = fmaxf(m1b, v);
            tlb = fmaxf(tlb, v);
        }
        float tl = fmaxf(tla, tlb);
        tl = fmaxf(tl, __shfl_xor(tl, 32, 64));
        if (half == 0) tmax[t * 128 + pb] = tl;
    };

    bf16x8 chA[4], clA[4], caA, chB[4], clB[4], caB;
    load_tile(0, chA, clA, caA);
    for (int t = 0; t < 32; t += 2) {         // double-buffered tile loop
        load_tile(t + 1, chB, clB, caB);
        screen_tile(t, chA, clA, caA);
        if (t + 2 < 32) load_tile(t + 2, chA, clA, caA);
        screen_tile(t + 1, chB, clB, caB);
    }

    // merge split chains (lex: exact first-max)
    float m1 = fmaxf(m1a, m1b);
    float m2 = fmaxf(fmaxf(m2a, m2b), fminf(m1a, m1b));
    int i1 = (m1b > m1a || (m1b == m1a && i1b < i1a)) ? i1b : i1a;
    // cross-half merge
    {
        float m1o = __shfl_xor(m1, 32, 64);
        float m2o = __shfl_xor(m2, 32, 64);
        int   i1o = __shfl_xor(i1, 32, 64);
        m2 = fmaxf(fmaxf(m2, m2o), fminf(m1, m1o));
        i1 = (m1o > m1 || (m1o == m1 && i1o < i1)) ? i1o : i1;
        m1 = fmaxf(m1, m1o);
        if (half == 0) fk[pb] = i1;
    }

    // Ballot rescan by owning wave: candidate tiles only, reference-bit-exact.
    // tmax/fk for this wave's points were written by this wave -> no barrier.
    {
        bool amb = (half == 0) && (m2 >= m1 - EPS_A_W);
        unsigned long long mask = __ballot(amb);
        while (mask) {
            int lp = __ffsll(mask) - 1;
            mask &= mask - 1;
            int p = (wave << 5) + lp;
            float thr = __shfl(m1, lp, 64) - EPS_T_W;
            const float* xrow = &xs[p * 65];
            float Aq = np_pairwise_sumsq64(xrow);
            unsigned long long best = ~0ULL;
            for (int t = 0; t < 32; ++t) {
                if (tmax[t * 128 + p] < thr) continue;   // wave-uniform branch
                if (lane < 32) {
                    int k = (t << 5) + lane;
                    const float* crow = cb + (size_t)k * 64;
                    float m = 0.0f;
                    #pragma unroll
                    for (int d = 0; d < 64; ++d) m = __fmaf_rn(xrow[d], crow[d], m);
                    float D = __fsub_rn(__fadd_rn(Aq, csum[k]), __fmul_rn(2.0f, m));
                    unsigned long long key =
                        ((unsigned long long)__float_as_uint(D) << 10) | (unsigned)k;
                    best = (key < best) ? key : best;
                }
            }
            #pragma unroll
            for (int off = 32; off > 0; off >>= 1) {
                unsigned long long o = __shfl_xor(best, off, 64);
                best = (o < best) ? o : best;
            }
            if (lane == 0) fk[p] = (int)(best & 1023ULL);
        }
    }
    __syncthreads();

    // indices + histogram
    if (tid < 128) {
        out[OUT_I_OFF + n0 + tid] = (float)fk[tid];
        atomicAdd(&hist[fk[tid]], 1u);
    }

    // Quantized gather (coalesced: one cb row per wave-instruction) fused with
    // SSE; q overwrites xs in place (each slot owned by exactly one thread).
    {
        double e = 0.0;
        #pragma unroll
        for (int it = 0; it < 32; ++it) {
            int i = tid + it * 256;
            int p = i >> 6, c = i & 63;           // c across lanes -> coalesced
            float q = cb[(size_t)fk[p] * 64 + c];
            float xv = xs[p * 65 + c];
            double df = (double)xv - (double)q;
            e = fma(df, df, e);
            xs[p * 65 + c] = q;
        }
        red[tid] = e;
    }
    __syncthreads();
    if (tid < 128) red[tid] += red[tid + 128];
    __syncthreads();
    if (tid < 64) {
        double v = red[tid] + red[tid + 64];
        #pragma unroll
        for (int off = 32; off > 0; off >>= 1) v += __shfl_down(v, off, 64);
        if (tid == 0) atomicAdd(sse, v);
    }
    // Quantized stores: p across lanes -> coalesced; LDS bank (p+c)%32 -> 2-way free.
    #pragma unroll
    for (int it = 0; it < 32; ++it) {
        int i = tid + it * 256;
        int p = i & 127, c = i >> 7;
        out[OUT_Q_OFF + (size_t)b * 65536 + (size_t)c * HW + hw0 + p] = xs[p * 65 + c];
    }

    // Last-block finalization. __syncthreads drains vmcnt -> this block's
    // hist/sse atomics are globally performed before the counter bump.
    __syncthreads();
    if (tid == 0) lastflag = (atomicAdd(counter, 1u) == NBLOCKS - 1) ? 1 : 0;
    __syncthreads();
    if (lastflag) {
        double s = 0.0;
        for (int i = tid; i < K_CODES; i += 256) {
            double p = (double)atomicAdd(&hist[i], 0u) / (double)N_PTS;
            s += p * log(p + 1e-10);
        }
        red[tid] = s;
        __syncthreads();
        for (int w = 128; w > 0; w >>= 1) {
            if (tid < w) red[tid] += red[tid + w];
            __syncthreads();
        }
        if (tid == 0) {
            out[OUT_P_OFF] = (float)exp(-red[0]);
            double sv = atomicAdd(sse, 0.0);
            out[0] = (float)(1.25 * sv / (double)Q_ELEMS);
        }
    }
}

extern "C" void kernel_launch(void* const* d_in, const int* in_sizes, int n_in,
                              void* d_out, int out_size, void* d_ws, size_t ws_size,
                              hipStream_t stream) {
    const float* latents = (const float*)d_in[0];
    const float* cb      = (const float*)d_in[1];
    float* out = (float*)d_out;
    char* ws = (char*)d_ws;

    unsigned int*   hist    = (unsigned int*)(ws + WS_HIST);
    unsigned int*   counter = (unsigned int*)(ws + WS_CNT);
    double*         sse     = (double*)(ws + WS_SSE);
    float*          csum    = (float*)(ws + WS_CSUM);
    unsigned short* cbp     = (unsigned short*)(ws + WS_CBP);

    vq_prep <<<32, 256, 0, stream>>>(cb, csum, cbp, hist, counter, sse);
    vq_main <<<NBLOCKS, 256, 0, stream>>>(latents, cb, csum, cbp, hist, sse, counter, out);
}

// Round 11
// 142.832 us; speedup vs baseline: 1.1011x; 1.0358x over previous
//
#include <hip/hip_runtime.h>

// Problem constants
#define N_PTS   65536      // B*H*W = 64*32*32
#define K_CODES 1024
#define C_DIM   64
#define HW      1024
#define Q_ELEMS 4194304
#define NBLOCKS 512        // vq_main grid (128 points per block)

// d_out layout (float32): [vq_loss(1) | quantized(4194304) | perplexity(1) | indices(65536)]
#define OUT_Q_OFF 1
#define OUT_P_OFF 4194305
#define OUT_I_OFF 4194306

// ws layout (bytes)
#define WS_HIST 0          // 1024 u32   (4096)
#define WS_CNT  4096       // 1 u32      (4)
#define WS_SSE  4104       // 1 double   (8)
#define WS_CSUM 4112       // 1024 f32   (4096)
#define WS_CBP  8208       // packed A-frags: 32 tiles * 9 slots * 512 shorts (294912)

// Screen metric w = x.c - csum/2 (argmin dist == argmax w). Proven thresholds
// (identical indices across R5-R10 structural variants):
#define EPS_A_W 7.5e-5f    // ambiguous if m2 >= m1 - EPS_A_W
#define EPS_T_W 2.0e-4f    // candidate tile if tmax >= m1 - EPS_T_W

typedef float f32x16 __attribute__((ext_vector_type(16)));
typedef short bf16x8 __attribute__((ext_vector_type(8)));

__device__ __forceinline__ unsigned short bf16rn(float f) {
    unsigned int u = __float_as_uint(f);
    return (unsigned short)((u + 0x7FFFu + ((u >> 16) & 1u)) >> 16);
}
__device__ __forceinline__ float bf16tof(unsigned short h) {
    return __uint_as_float(((unsigned int)h) << 16);
}

// numpy pairwise sum (n=64): 8 accumulators striding 8, then pairwise combine.
__device__ __forceinline__ float np_pairwise_sumsq64(const float* a) {
    float r[8];
    #pragma unroll
    for (int j = 0; j < 8; ++j) r[j] = __fmul_rn(a[j], a[j]);
    #pragma unroll
    for (int i = 8; i < 64; i += 8) {
        #pragma unroll
        for (int j = 0; j < 8; ++j)
            r[j] = __fadd_rn(r[j], __fmul_rn(a[i + j], a[i + j]));
    }
    return __fadd_rn(__fadd_rn(__fadd_rn(r[0], r[1]), __fadd_rn(r[2], r[3])),
                     __fadd_rn(__fadd_rn(r[4], r[5]), __fadd_rn(r[6], r[7])));
}

// Prep: one block per 32-code tile; LDS-staged coalesced reads; also zeroes
// hist/counter/sse (no memset node). Pack phase runs 576 parallel units.
__global__ void vq_prep(const float* __restrict__ cb, float* __restrict__ csum,
                        unsigned short* __restrict__ cbp,
                        unsigned int* __restrict__ hist,
                        unsigned int* __restrict__ counter,
                        double* __restrict__ sse) {
    __shared__ float rs[32 * 65];
    __shared__ float csl[32];
    const int t = blockIdx.x, tid = threadIdx.x;
    if (tid < 32) hist[t * 32 + tid] = 0u;
    if (t == 0 && tid == 0) { *counter = 0u; *sse = 0.0; }
    const float* src = cb + (size_t)t * 2048;
    for (int i = tid; i < 2048; i += 256) {
        int row = i >> 6, d = i & 63;
        rs[row * 65 + d] = src[i];
    }
    __syncthreads();
    if (tid < 32) {
        float cs = np_pairwise_sumsq64(&rs[tid * 65]);
        csum[t * 32 + tid] = cs;
        csl[tid] = cs;
    }
    __syncthreads();
    // 576 pack units: u -> (slot s, lane); slots 0..7 = chunk hi/lo, slot 8 = csum
    for (int u = tid; u < 576; u += 256) {
        int s = u >> 6, lane = u & 63, l31 = lane & 31, half = lane >> 5;
        bf16x8 v8;
        if (s < 8) {
            int c = s >> 1, lo = s & 1;
            const float* r = &rs[l31 * 65 + c * 16 + half * 8];
            #pragma unroll
            for (int j = 0; j < 8; ++j) {
                float f = r[j];
                unsigned short h = bf16rn(f);
                v8[j] = lo ? (short)bf16rn(f - bf16tof(h)) : (short)h;
            }
        } else {
            #pragma unroll
            for (int j = 0; j < 8; ++j) v8[j] = 0;
            if (half == 0) v8[0] = (short)bf16rn(-0.5f * csl[l31]);
        }
        *(bf16x8*)(cbp + (size_t)t * 4608 + (size_t)s * 512 + lane * 8) = v8;
    }
}

// Main (R7 verbatim, measured 73us): block = 128 points, 4 waves; each wave
// owns 32 points, screens all 32 code-tiles with double-buffered packed
// A-frag loads + 2 MFMA chains (5/8), single argmax chain. tmax bounds the
// exact rescan; block-shared ambiguous list load-balanced across waves,
// reference-bit-exact f32 pipeline. Last block computes perplexity + loss.
// NOTE: do not split argmax chains or per-wave ballot rescans — both
// regressed (R10: 88us vs this structure's 73us).
__global__ __launch_bounds__(256, 2) void vq_main(
        const float* __restrict__ latents,
        const float* __restrict__ cb,
        const float* __restrict__ csum,
        const unsigned short* __restrict__ cbp,
        unsigned int* __restrict__ hist,
        double* __restrict__ sse,
        unsigned int* __restrict__ counter,
        float* __restrict__ out) {
    __shared__ float xs[128 * 65];            // 33.3 KB, stride 65
    __shared__ float tmax[32 * 128];          // 16 KB per-(tile,point) screen max
    __shared__ float m1f[128];
    __shared__ int   fk[128], ambig[128], acount;
    __shared__ int   lastflag;
    __shared__ double red[256];               // SSE partials + finalize

    const int tid  = threadIdx.x;
    const int lane = tid & 63, wave = tid >> 6;
    const int n0 = blockIdx.x * 128;
    const int b = n0 >> 10, hw0 = n0 & 1023;
    const float* xg = latents + (size_t)b * C_DIM * HW + hw0;

    for (int i = tid; i < 128 * 64; i += 256) {
        int p = i & 127, d = i >> 7;
        xs[p * 65 + d] = xg[(size_t)d * HW + p];
    }
    if (tid == 0) acount = 0;
    __syncthreads();

    // B-frags: col = lane&31 -> point, k = (lane>>5)*8 + j
    const int l31 = lane & 31, half = lane >> 5;
    const int pb = (wave << 5) + l31;
    bf16x8 xh[4], xl[4], x4;
    #pragma unroll
    for (int c = 0; c < 4; ++c)
        #pragma unroll
        for (int j = 0; j < 8; ++j) {
            float f = xs[pb * 65 + c * 16 + half * 8 + j];
            unsigned short h = bf16rn(f);
            xh[c][j] = (short)h;
            xl[c][j] = (short)bf16rn(f - bf16tof(h));
        }
    #pragma unroll
    for (int j = 0; j < 8; ++j) x4[j] = 0;
    if (half == 0) x4[0] = (short)0x3F80;     // bf16(1.0) at k=64

    float m1 = -3e38f, m2 = -3e38f;
    int i1 = 0;
    const int RC[16] = {0,1,2,3,8,9,10,11,16,17,18,19,24,25,26,27};
    const int rh4 = half * 4;
    const bf16x8* base = (const bf16x8*)cbp;

    auto screen_tile = [&](int t, const bf16x8* ch, const bf16x8* cl, bf16x8 ca) {
        f32x16 accA, accB;
        #pragma unroll
        for (int r = 0; r < 16; ++r) { accA[r] = 0.0f; accB[r] = 0.0f; }
        #pragma unroll
        for (int c = 0; c < 4; ++c)
            accA = __builtin_amdgcn_mfma_f32_32x32x16_bf16(ch[c], xh[c], accA, 0, 0, 0);
        accA = __builtin_amdgcn_mfma_f32_32x32x16_bf16(ca, x4, accA, 0, 0, 0);
        #pragma unroll
        for (int c = 0; c < 4; ++c)
            accB = __builtin_amdgcn_mfma_f32_32x32x16_bf16(ch[c], xl[c], accB, 0, 0, 0);
        #pragma unroll
        for (int c = 0; c < 4; ++c)
            accB = __builtin_amdgcn_mfma_f32_32x32x16_bf16(cl[c], xh[c], accB, 0, 0, 0);
        float tl = -3e38f;
        const int tb = t << 5;
        #pragma unroll
        for (int r = 0; r < 16; ++r) {
            float v = __fadd_rn(accA[r], accB[r]);   // w = x.c - csum/2
            int k = tb + RC[r] + rh4;
            m2 = fmaxf(m2, fminf(m1, v));
            i1 = (v > m1) ? k : i1;           // strict >: first-max = ref tie-break
            m1 = fmaxf(m1, v);
            tl = fmaxf(tl, v);
        }
        tl = fmaxf(tl, __shfl_xor(tl, 32, 64));
        if (half == 0) tmax[t * 128 + pb] = tl;
    };
    auto load_tile = [&](int t, bf16x8* ch, bf16x8* cl, bf16x8& ca) {
        const bf16x8* bp = base + (size_t)t * 576 + lane;
        #pragma unroll
        for (int c = 0; c < 4; ++c) {
            ch[c] = bp[c * 128];
            cl[c] = bp[c * 128 + 64];
        }
        ca = bp[512];
    };

    bf16x8 chA[4], clA[4], caA, chB[4], clB[4], caB;
    load_tile(0, chA, clA, caA);
    for (int t = 0; t < 32; t += 2) {         // double-buffered tile loop
        load_tile(t + 1, chB, clB, caB);
        screen_tile(t, chA, clA, caA);
        if (t + 2 < 32) load_tile(t + 2, chA, clA, caA);
        screen_tile(t + 1, chB, clB, caB);
    }
    // cross-half merge; ties resolve via ambiguous path
    {
        float m1o = __shfl_xor(m1, 32, 64);
        float m2o = __shfl_xor(m2, 32, 64);
        int   i1o = __shfl_xor(i1, 32, 64);
        m2 = fmaxf(fmaxf(m2, m2o), fminf(m1, m1o));
        i1 = (m1o > m1) ? i1o : i1;
        m1 = fmaxf(m1, m1o);
        if (half == 0) {
            m1f[pb] = m1;
            fk[pb] = i1;
            if (m2 >= m1 - EPS_A_W) {
                int a = atomicAdd(&acount, 1);
                ambig[a] = pb;
            }
        }
    }
    __syncthreads();

    // Exact rescan: one wave per ambiguous point (block-shared list ->
    // load-balanced), candidate tiles only. Reference-bit-exact:
    // dist = fl32(fl32(A+csum[k]) - fl32(2*seqFMA)).
    for (int a = wave; a < acount; a += 4) {
        int p = ambig[a];
        const float* xrow = &xs[p * 65];
        float Aq = np_pairwise_sumsq64(xrow);
        float thr = m1f[p] - EPS_T_W;
        unsigned long long best = ~0ULL;
        for (int t = 0; t < 32; ++t) {
            if (tmax[t * 128 + p] < thr) continue;   // wave-uniform branch
            if (lane < 32) {
                int k = (t << 5) + lane;
                const float* crow = cb + (size_t)k * 64;
                float m = 0.0f;
                #pragma unroll
                for (int d = 0; d < 64; ++d) m = __fmaf_rn(xrow[d], crow[d], m);
                float D = __fsub_rn(__fadd_rn(Aq, csum[k]), __fmul_rn(2.0f, m));
                unsigned long long key =
                    ((unsigned long long)__float_as_uint(D) << 10) | (unsigned)k;
                best = (key < best) ? key : best;
            }
        }
        #pragma unroll
        for (int off = 32; off > 0; off >>= 1) {
            unsigned long long o = __shfl_xor(best, off, 64);
            best = (o < best) ? o : best;
        }
        if (lane == 0) fk[p] = (int)(best & 1023ULL);
    }
    __syncthreads();

    // indices + histogram + SSE (R7 epilogue, verbatim)
    if (tid < 128) {
        int myk = fk[tid];
        out[OUT_I_OFF + n0 + tid] = (float)myk;
        atomicAdd(&hist[myk], 1u);
        const float* crow = cb + (size_t)myk * 64;
        const float* xrow = &xs[tid * 65];
        double e = 0.0;
        #pragma unroll
        for (int d = 0; d < 64; ++d) {
            double df = (double)xrow[d] - (double)crow[d];
            e = fma(df, df, e);
        }
        red[tid] = e;
    }
    __syncthreads();
    if (tid < 64) {
        double v = red[tid] + red[tid + 64];
        #pragma unroll
        for (int off = 32; off > 0; off >>= 1) v += __shfl_down(v, off, 64);
        if (tid == 0) atomicAdd(sse, v);
    }
    // quantized [B,C,H,W]: coalesced 128-float store rows per c
    for (int i = tid; i < 128 * 64; i += 256) {
        int p = i & 127, c = i >> 7;
        out[OUT_Q_OFF + (size_t)b * 65536 + (size_t)c * HW + hw0 + p] =
            cb[(size_t)fk[p] * 64 + c];
    }

    // Last-block finalization. __syncthreads drains vmcnt -> this block's
    // hist/sse atomics are globally performed before the counter bump.
    __syncthreads();
    if (tid == 0) lastflag = (atomicAdd(counter, 1u) == NBLOCKS - 1) ? 1 : 0;
    __syncthreads();
    if (lastflag) {
        double s = 0.0;
        for (int i = tid; i < K_CODES; i += 256) {
            double p = (double)atomicAdd(&hist[i], 0u) / (double)N_PTS;
            s += p * log(p + 1e-10);
        }
        red[tid] = s;
        __syncthreads();
        for (int w = 128; w > 0; w >>= 1) {
            if (tid < w) red[tid] += red[tid + w];
            __syncthreads();
        }
        if (tid == 0) {
            out[OUT_P_OFF] = (float)exp(-red[0]);
            double sv = atomicAdd(sse, 0.0);
            out[0] = (float)(1.25 * sv / (double)Q_ELEMS);
        }
    }
}

extern "C" void kernel_launch(void* const* d_in, const int* in_sizes, int n_in,
                              void* d_out, int out_size, void* d_ws, size_t ws_size,
                              hipStream_t stream) {
    const float* latents = (const float*)d_in[0];
    const float* cb      = (const float*)d_in[1];
    float* out = (float*)d_out;
    char* ws = (char*)d_ws;

    unsigned int*   hist    = (unsigned int*)(ws + WS_HIST);
    unsigned int*   counter = (unsigned int*)(ws + WS_CNT);
    double*         sse     = (double*)(ws + WS_SSE);
    float*          csum    = (float*)(ws + WS_CSUM);
    unsigned short* cbp     = (unsigned short*)(ws + WS_CBP);

    vq_prep <<<32, 256, 0, stream>>>(cb, csum, cbp, hist, counter, sse);
    vq_main <<<NBLOCKS, 256, 0, stream>>>(latents, cb, csum, cbp, hist, sse, counter, out);
}